// Round 1
// baseline (218.081 us; speedup 1.0000x reference)
//
#include <hip/hip_runtime.h>
#include <hip/hip_bf16.h>

typedef __bf16 bf16;
typedef __bf16 bf16x8 __attribute__((ext_vector_type(8)));
typedef __bf16 bf16x4 __attribute__((ext_vector_type(4)));
typedef float  f32x4  __attribute__((ext_vector_type(4)));

// async global->LDS, 16B per lane. LDS dest is wave-uniform base + lane*16.
#define GLD_LDS(g, l)                                                        \
  __builtin_amdgcn_global_load_lds(                                          \
      (const __attribute__((address_space(1))) void*)(g),                    \
      (__attribute__((address_space(3))) void*)(l), 16, 0, 0)

// ---------------------------------------------------------------------------
// C = A (MxK, row-major) * B^T (B is NxK row-major) ; bf16 in, fp32 acc.
// 128x128 tile, BK=32, 4 waves (2x2), 16x16x32 bf16 MFMA, m97 structure.
// EPI==0: store bf16 to Cb.  EPI==1: store fp32 (+bias) to Cf.
// M,N % 128 == 0, K % 32 == 0.
// ---------------------------------------------------------------------------
template <int EPI>
__global__ void gemm_bt(const bf16* __restrict__ A, const bf16* __restrict__ B,
                        bf16* __restrict__ Cb, float* __restrict__ Cf,
                        const float* __restrict__ bias_p,
                        int M, int N, int K) {
  __shared__ bf16 As[128 * 32];
  __shared__ bf16 Bs[128 * 32];

  const int tid  = threadIdx.x;      // 0..255
  const int lane = tid & 63;
  const int wave = tid >> 6;         // 0..3
  const int wr = wave >> 1;          // wave row  (0..1) -> 64 rows each
  const int wc = wave & 1;           // wave col  (0..1) -> 64 cols each
  const int fr = lane & 15;          // fragment row/col within 16
  const int fq = lane >> 4;          // 0..3 -> k-subslice / acc row group

  const int row0 = blockIdx.y * 128; // output rows  (A rows)
  const int col0 = blockIdx.x * 128; // output cols  (B rows)

  f32x4 acc[4][4] = {};

  // Staging: tile is 128 rows x 32 cols bf16 = 8192 B; 256 thr x 16 B = 4096 B
  // per issue -> 2 issues per operand. chunk c covers row c>>2, cols (c&3)*8.
  const int c0 = tid, c1 = 256 + tid;
  const bf16* Ag0 = A + (size_t)(row0 + (c0 >> 2)) * K + (c0 & 3) * 8;
  const bf16* Ag1 = A + (size_t)(row0 + (c1 >> 2)) * K + (c1 & 3) * 8;
  const bf16* Bg0 = B + (size_t)(col0 + (c0 >> 2)) * K + (c0 & 3) * 8;
  const bf16* Bg1 = B + (size_t)(col0 + (c1 >> 2)) * K + (c1 & 3) * 8;
  bf16* Al0 = As + (wave * 64) * 8;          // wave-uniform LDS bases
  bf16* Al1 = As + (256 + wave * 64) * 8;
  bf16* Bl0 = Bs + (wave * 64) * 8;
  bf16* Bl1 = Bs + (256 + wave * 64) * 8;

  for (int k0 = 0; k0 < K; k0 += 32) {
    GLD_LDS(Ag0 + k0, Al0);
    GLD_LDS(Ag1 + k0, Al1);
    GLD_LDS(Bg0 + k0, Bl0);
    GLD_LDS(Bg1 + k0, Bl1);
    __syncthreads();  // drains vmcnt(0) then barrier

    bf16x8 af[4], bg[4];
#pragma unroll
    for (int m = 0; m < 4; ++m)
      af[m] = *(const bf16x8*)&As[(wr * 64 + m * 16 + fr) * 32 + fq * 8];
#pragma unroll
    for (int n = 0; n < 4; ++n)
      bg[n] = *(const bf16x8*)&Bs[(wc * 64 + n * 16 + fr) * 32 + fq * 8];

#pragma unroll
    for (int m = 0; m < 4; ++m)
#pragma unroll
      for (int n = 0; n < 4; ++n)
        acc[m][n] = __builtin_amdgcn_mfma_f32_16x16x32_bf16(af[m], bg[n],
                                                            acc[m][n], 0, 0, 0);
    __syncthreads();
  }

  const float bias = (EPI == 1) ? bias_p[0] : 0.0f;
  // C/D layout (verified m89/m91): col = lane&15, row = (lane>>4)*4 + reg.
#pragma unroll
  for (int m = 0; m < 4; ++m) {
#pragma unroll
    for (int n = 0; n < 4; ++n) {
      const int r  = row0 + wr * 64 + m * 16 + fq * 4;
      const int cc = col0 + wc * 64 + n * 16 + fr;
#pragma unroll
      for (int j = 0; j < 4; ++j) {
        if (EPI == 1)
          Cf[(size_t)(r + j) * N + cc] = acc[m][n][j] + bias;
        else
          Cb[(size_t)(r + j) * N + cc] = (bf16)acc[m][n][j];
      }
    }
  }
}

// fp32 -> bf16 cast, 4 elems/thread (vectorized 16B load / 8B store)
__global__ void cvt_f32_bf16(const float* __restrict__ in, bf16* __restrict__ out,
                             int n4) {
  int i = blockIdx.x * blockDim.x + threadIdx.x;
  if (i >= n4) return;
  const float4 v = ((const float4*)in)[i];
  bf16x4 o;
  o[0] = (bf16)v.x; o[1] = (bf16)v.y; o[2] = (bf16)v.z; o[3] = (bf16)v.w;
  ((bf16x4*)out)[i] = o;
}

// Wt[n][k] = (bf16) W[k][n], 1024x1024, LDS 32x32 tile (+1 pad)
__global__ void transpose_cvt_w(const float* __restrict__ W, bf16* __restrict__ Wt) {
  __shared__ float s[32][33];
  const int tx = threadIdx.x & 31;
  const int ty = threadIdx.x >> 5;  // 0..7
  const int n0 = blockIdx.x * 32;
  const int k0 = blockIdx.y * 32;
#pragma unroll
  for (int p = 0; p < 4; ++p)
    s[ty + p * 8][tx] = W[(size_t)(k0 + ty + p * 8) * 1024 + n0 + tx];
  __syncthreads();
#pragma unroll
  for (int p = 0; p < 4; ++p)
    Wt[(size_t)(n0 + ty + p * 8) * 1024 + k0 + tx] = (bf16)s[tx][ty + p * 8];
}

extern "C" void kernel_launch(void* const* d_in, const int* in_sizes, int n_in,
                              void* d_out, int out_size, void* d_ws, size_t ws_size,
                              hipStream_t stream) {
  const float* X = (const float*)d_in[0];   // (8192, 1024)
  const float* W = (const float*)d_in[1];   // (1024, 1024)
  const float* b = (const float*)d_in[2];   // (1,)
  float* out = (float*)d_out;               // (8192, 8192)

  const int Nn = 8192, D = 1024;

  // workspace: Xb 16MB | XWb 16MB | Wt 2MB  (all rewritten every call)
  char* ws = (char*)d_ws;
  bf16* Xb  = (bf16*)(ws);
  bf16* XWb = (bf16*)(ws + (size_t)16 * 1024 * 1024);
  bf16* Wt  = (bf16*)(ws + (size_t)32 * 1024 * 1024);

  // 1) X -> bf16
  cvt_f32_bf16<<<(Nn * D / 4 + 255) / 256, 256, 0, stream>>>(X, Xb, Nn * D / 4);
  // 2) W -> Wt (transposed, bf16)
  transpose_cvt_w<<<dim3(D / 32, D / 32), 256, 0, stream>>>(W, Wt);
  // 3) XW = Xb * Wt^T   (8192x1024) -> bf16
  gemm_bt<0><<<dim3(D / 128, Nn / 128), 256, 0, stream>>>(Xb, Wt, XWb, nullptr,
                                                          nullptr, Nn, D, D);
  // 4) out = XWb * Xb^T + b  (8192x8192) fp32
  gemm_bt<1><<<dim3(Nn / 128, Nn / 128), 256, 0, stream>>>(XWb, Xb, nullptr, out,
                                                           b, Nn, Nn, D);
}

// Round 2
// 208.829 us; speedup vs baseline: 1.0443x; 1.0443x over previous
//
#include <hip/hip_runtime.h>
#include <hip/hip_bf16.h>

typedef __bf16 bf16;
typedef __bf16 bf16x8 __attribute__((ext_vector_type(8)));
typedef __bf16 bf16x4 __attribute__((ext_vector_type(4)));
typedef float  f32x4  __attribute__((ext_vector_type(4)));

#define GLD_LDS(g, l)                                                        \
  __builtin_amdgcn_global_load_lds(                                          \
      (const __attribute__((address_space(1))) void*)(g),                    \
      (__attribute__((address_space(3))) void*)(l), 16, 0, 0)

#define BAR()   asm volatile("s_barrier" ::: "memory")
#define WLG()   asm volatile("s_waitcnt lgkmcnt(0)" ::: "memory")
#define WVM4()  asm volatile("s_waitcnt vmcnt(4)" ::: "memory")
#define WVM0()  asm volatile("s_waitcnt vmcnt(0)" ::: "memory")
#define PRIO1() __builtin_amdgcn_s_setprio(1)
#define PRIO0() __builtin_amdgcn_s_setprio(0)

// ---------------------------------------------------------------------------
// 256x256 tile, BK=64, 8 waves (2Mx4N), 8-phase schedule, counted vmcnt,
// st-swizzled LDS (XOR bits 4-6 of byte offset with row&7).
// C = A (MxK rm) * B^T (B NxK rm) + bias, fp32 out.  M,N %256==0, K%128==0.
// LDS: A bufs @ byte 0 (2x32KB), B bufs @ byte 65536 (2x32KB) = 128 KiB.
// Staging: per half-tile (128 rows x 64 cols bf16 = 16KB) = 2 gld_lds/thread.
//   Per-lane global src is pre-swizzled: col16 = (lane&7)^(lane>>3), so the
//   linear gld_lds write lands data at LDS[row][col ^ ((row&7)<<4 bytes)].
// Ledger (iteration = tiles T,T+1; buf = t&1):
//   ph1: stage B0(T+1)   ph2: B1(T+1)   ph4: A0,A1(T+2) + vmcnt(4)
//   ph5: B0(T+2)         ph6: B1(T+2)   ph8: A0,A1(T+3) + vmcnt(4)
//   last iters: vmcnt(0) where no stage. All region overwrites occur >=1
//   barrier after that region's last ds_read of the previous occupant.
// ---------------------------------------------------------------------------
__global__ __launch_bounds__(512, 2)
void gemm256(const bf16* __restrict__ A, const bf16* __restrict__ B,
             float* __restrict__ C, const float* __restrict__ bias_p,
             int M, int N, int K) {
  extern __shared__ bf16 lds[];
  const int tid  = threadIdx.x;
  const int lane = tid & 63, wave = tid >> 6;
  const int wm = wave >> 2, wn = wave & 3;       // 2 x 4 waves
  const int fr = lane & 15, fq = lane >> 4;
  const int xm = (fr & 7) << 4;                  // read-side swizzle mask

  // XCD-aware block swizzle (nwg divisible by 8)
  const int nwg = gridDim.x;
  const int bid = blockIdx.x;
  const int swz = (bid & 7) * (nwg >> 3) + (bid >> 3);
  const int gx  = N >> 8;
  const int row0 = (swz / gx) << 8, col0 = (swz % gx) << 8;

  // per-lane staging source bases (pre-swizzled column)
  const int srow = wave * 8 + (lane >> 3);
  const int scol = ((lane & 7) ^ (lane >> 3)) * 8;
  const bf16* Agl = A + (size_t)(row0 + srow) * K + scol;
  const bf16* Bgl = B + (size_t)(col0 + srow) * K + scol;

  // stage one half-tile (h=0/1) of tile t of operand at lds element base tb
#define STG(gl, tb, t, h)                                                    \
  do {                                                                       \
    const size_t _k = (size_t)(t) * 64;                                      \
    GLD_LDS((gl) + (size_t)((h) * 128) * K + _k,                             \
            lds + (tb) + ((t) & 1) * 16384 + (h) * 8192 + wave * 512);       \
    GLD_LDS((gl) + (size_t)((h) * 128 + 64) * K + _k,                        \
            lds + (tb) + ((t) & 1) * 16384 + (h) * 8192 + 4096 + wave * 512);\
  } while (0)

  const char* ldsc = (const char*)lds;
  const int acol0 = (fq * 16) ^ xm, acol1 = (64 + fq * 16) ^ xm;

  f32x4  acc[8][4] = {};
  bf16x8 af[4][2], bg[2][2];

#define LDA(mg, p)                                                           \
  do {                                                                       \
    _Pragma("unroll") for (int m_ = 0; m_ < 4; ++m_) {                       \
      const int r_ = (wm * 128 + ((mg) * 4 + m_) * 16 + fr) * 128;           \
      af[m_][0] = *(const bf16x8*)(ldsc + (p) * 32768 + r_ + acol0);         \
      af[m_][1] = *(const bf16x8*)(ldsc + (p) * 32768 + r_ + acol1);         \
    }                                                                        \
  } while (0)

#define LDB(np, p)                                                           \
  do {                                                                       \
    _Pragma("unroll") for (int n_ = 0; n_ < 2; ++n_) {                       \
      const int r_ = (wn * 64 + ((np) * 2 + n_) * 16 + fr) * 128;            \
      bg[n_][0] = *(const bf16x8*)(ldsc + 65536 + (p) * 32768 + r_ + acol0); \
      bg[n_][1] = *(const bf16x8*)(ldsc + 65536 + (p) * 32768 + r_ + acol1); \
    }                                                                        \
  } while (0)

#define MM(mg, np)                                                           \
  do {                                                                       \
    _Pragma("unroll") for (int kk_ = 0; kk_ < 2; ++kk_)                      \
      _Pragma("unroll") for (int m_ = 0; m_ < 4; ++m_)                       \
        _Pragma("unroll") for (int n_ = 0; n_ < 2; ++n_)                     \
          acc[(mg) * 4 + m_][(np) * 2 + n_] =                                \
              __builtin_amdgcn_mfma_f32_16x16x32_bf16(                       \
                  af[m_][kk_], bg[n_][kk_],                                  \
                  acc[(mg) * 4 + m_][(np) * 2 + n_], 0, 0, 0);               \
  } while (0)

  // prologue: tile0 (A0,A1,B0,B1) + tile1 (A0,A1); leave B(1) for ph1/ph2
  STG(Agl, 0, 0, 0); STG(Agl, 0, 0, 1);
  STG(Bgl, 32768, 0, 0); STG(Bgl, 32768, 0, 1);
  STG(Agl, 0, 1, 0); STG(Agl, 0, 1, 1);
  WVM4(); BAR();

  const int NT = K >> 6;
  for (int T = 0; T < NT; T += 2) {
    const bool s2 = (T + 2 < NT), s3 = (T + 3 < NT);
    // ph1
    LDA(0, 0); LDB(0, 0);
    STG(Bgl, 32768, T + 1, 0);
    BAR(); WLG(); PRIO1(); MM(0, 0); PRIO0(); BAR();
    // ph2
    LDB(1, 0);
    STG(Bgl, 32768, T + 1, 1);
    BAR(); WLG(); PRIO1(); MM(0, 1); PRIO0(); BAR();
    // ph3
    LDA(1, 0); LDB(0, 0);
    BAR(); WLG(); PRIO1(); MM(1, 0); PRIO0(); BAR();
    // ph4
    LDB(1, 0);
    if (s2) { STG(Agl, 0, T + 2, 0); STG(Agl, 0, T + 2, 1); }
    BAR(); WLG(); PRIO1(); MM(1, 1); PRIO0();
    if (s2) { WVM4(); } else { WVM0(); }
    BAR();
    // ph5
    LDA(0, 1); LDB(0, 1);
    if (s2) STG(Bgl, 32768, T + 2, 0);
    BAR(); WLG(); PRIO1(); MM(0, 0); PRIO0(); BAR();
    // ph6
    LDB(1, 1);
    if (s2) STG(Bgl, 32768, T + 2, 1);
    BAR(); WLG(); PRIO1(); MM(0, 1); PRIO0(); BAR();
    // ph7
    LDA(1, 1); LDB(0, 1);
    BAR(); WLG(); PRIO1(); MM(1, 0); PRIO0(); BAR();
    // ph8
    LDB(1, 1);
    if (s3) { STG(Agl, 0, T + 3, 0); STG(Agl, 0, T + 3, 1); }
    BAR(); WLG(); PRIO1(); MM(1, 1); PRIO0();
    if (s3) { WVM4(); } else { WVM0(); }
    BAR();
  }

  const float bias = bias_p[0];
#pragma unroll
  for (int m = 0; m < 8; ++m) {
#pragma unroll
    for (int n = 0; n < 4; ++n) {
      const int r = row0 + wm * 128 + m * 16 + fq * 4;
      const int c = col0 + wn * 64 + n * 16 + fr;
#pragma unroll
      for (int j = 0; j < 4; ++j)
        C[(size_t)(r + j) * N + c] = acc[m][n][j] + bias;
    }
  }
#undef STG
#undef LDA
#undef LDB
#undef MM
}

// ---------------------------------------------------------------------------
// m97-structure 128x128 GEMM (kept for the small XW=X*W^T, bf16 out)
// ---------------------------------------------------------------------------
__global__ void gemm_bt(const bf16* __restrict__ A, const bf16* __restrict__ B,
                        bf16* __restrict__ Cb, int M, int N, int K) {
  __shared__ bf16 As[128 * 32];
  __shared__ bf16 Bs[128 * 32];
  const int tid  = threadIdx.x;
  const int lane = tid & 63;
  const int wave = tid >> 6;
  const int wr = wave >> 1, wc = wave & 1;
  const int fr = lane & 15, fq = lane >> 4;
  const int row0 = blockIdx.y * 128, col0 = blockIdx.x * 128;

  f32x4 acc[4][4] = {};
  const int c0 = tid, c1 = 256 + tid;
  const bf16* Ag0 = A + (size_t)(row0 + (c0 >> 2)) * K + (c0 & 3) * 8;
  const bf16* Ag1 = A + (size_t)(row0 + (c1 >> 2)) * K + (c1 & 3) * 8;
  const bf16* Bg0 = B + (size_t)(col0 + (c0 >> 2)) * K + (c0 & 3) * 8;
  const bf16* Bg1 = B + (size_t)(col0 + (c1 >> 2)) * K + (c1 & 3) * 8;
  bf16* Al0 = As + (wave * 64) * 8;
  bf16* Al1 = As + (256 + wave * 64) * 8;
  bf16* Bl0 = Bs + (wave * 64) * 8;
  bf16* Bl1 = Bs + (256 + wave * 64) * 8;

  for (int k0 = 0; k0 < K; k0 += 32) {
    GLD_LDS(Ag0 + k0, Al0);
    GLD_LDS(Ag1 + k0, Al1);
    GLD_LDS(Bg0 + k0, Bl0);
    GLD_LDS(Bg1 + k0, Bl1);
    __syncthreads();
    bf16x8 af[4], bgf[4];
#pragma unroll
    for (int m = 0; m < 4; ++m)
      af[m] = *(const bf16x8*)&As[(wr * 64 + m * 16 + fr) * 32 + fq * 8];
#pragma unroll
    for (int n = 0; n < 4; ++n)
      bgf[n] = *(const bf16x8*)&Bs[(wc * 64 + n * 16 + fr) * 32 + fq * 8];
#pragma unroll
    for (int m = 0; m < 4; ++m)
#pragma unroll
      for (int n = 0; n < 4; ++n)
        acc[m][n] = __builtin_amdgcn_mfma_f32_16x16x32_bf16(af[m], bgf[n],
                                                            acc[m][n], 0, 0, 0);
    __syncthreads();
  }
#pragma unroll
  for (int m = 0; m < 4; ++m)
#pragma unroll
    for (int n = 0; n < 4; ++n) {
      const int r  = row0 + wr * 64 + m * 16 + fq * 4;
      const int cc = col0 + wc * 64 + n * 16 + fr;
#pragma unroll
      for (int j = 0; j < 4; ++j)
        Cb[(size_t)(r + j) * N + cc] = (bf16)acc[m][n][j];
    }
}

__global__ void cvt_f32_bf16(const float* __restrict__ in, bf16* __restrict__ out,
                             int n4) {
  int i = blockIdx.x * blockDim.x + threadIdx.x;
  if (i >= n4) return;
  const float4 v = ((const float4*)in)[i];
  bf16x4 o;
  o[0] = (bf16)v.x; o[1] = (bf16)v.y; o[2] = (bf16)v.z; o[3] = (bf16)v.w;
  ((bf16x4*)out)[i] = o;
}

__global__ void transpose_cvt_w(const float* __restrict__ W, bf16* __restrict__ Wt) {
  __shared__ float s[32][33];
  const int tx = threadIdx.x & 31;
  const int ty = threadIdx.x >> 5;
  const int n0 = blockIdx.x * 32;
  const int k0 = blockIdx.y * 32;
#pragma unroll
  for (int p = 0; p < 4; ++p)
    s[ty + p * 8][tx] = W[(size_t)(k0 + ty + p * 8) * 1024 + n0 + tx];
  __syncthreads();
#pragma unroll
  for (int p = 0; p < 4; ++p)
    Wt[(size_t)(n0 + ty + p * 8) * 1024 + k0 + tx] = (bf16)s[tx][ty + p * 8];
}

extern "C" void kernel_launch(void* const* d_in, const int* in_sizes, int n_in,
                              void* d_out, int out_size, void* d_ws, size_t ws_size,
                              hipStream_t stream) {
  const float* X = (const float*)d_in[0];   // (8192, 1024)
  const float* W = (const float*)d_in[1];   // (1024, 1024)
  const float* b = (const float*)d_in[2];   // (1,)
  float* out = (float*)d_out;               // (8192, 8192)

  const int Nn = 8192, D = 1024;
  char* ws = (char*)d_ws;
  bf16* Xb  = (bf16*)(ws);
  bf16* XWb = (bf16*)(ws + (size_t)16 * 1024 * 1024);
  bf16* Wt  = (bf16*)(ws + (size_t)32 * 1024 * 1024);

  cvt_f32_bf16<<<(Nn * D / 4 + 255) / 256, 256, 0, stream>>>(X, Xb, Nn * D / 4);
  transpose_cvt_w<<<dim3(D / 32, D / 32), 256, 0, stream>>>(W, Wt);
  gemm_bt<<<dim3(D / 128, Nn / 128), 256, 0, stream>>>(Xb, Wt, XWb, Nn, D, D);
  gemm256<<<(Nn / 256) * (Nn / 256), 512, 131072, stream>>>(XWb, Xb, out, b,
                                                            Nn, Nn, D);
}

// Round 3
// 199.206 us; speedup vs baseline: 1.0948x; 1.0483x over previous
//
#include <hip/hip_runtime.h>
#include <hip/hip_bf16.h>

typedef __bf16 bf16;
typedef __bf16 bf16x8 __attribute__((ext_vector_type(8)));
typedef __bf16 bf16x4 __attribute__((ext_vector_type(4)));
typedef float  f32x4  __attribute__((ext_vector_type(4)));

#define GLD_LDS(g, l)                                                        \
  __builtin_amdgcn_global_load_lds(                                          \
      (const __attribute__((address_space(1))) void*)(g),                    \
      (__attribute__((address_space(3))) void*)(l), 16, 0, 0)

#define BAR()   asm volatile("s_barrier" ::: "memory")
#define WVM4()  asm volatile("s_waitcnt vmcnt(4)" ::: "memory")
#define WVM0()  asm volatile("s_waitcnt vmcnt(0)" ::: "memory")
#define PRIO1() __builtin_amdgcn_s_setprio(1)
#define PRIO0() __builtin_amdgcn_s_setprio(0)

// ---------------------------------------------------------------------------
// 256x256 tile, BK=64, 8 waves (2Mx4N), 8-phase, counted vmcnt, XOR-swizzled
// LDS (bits 4-6 of byte addr ^= row&7), immediate-offset ds_reads off 4 base
// pointers (kk=1 base = kk=0 base ^ 64; all imm deltas 2048-aligned so the
// XOR bits are never touched by the adds).
// C = A (MxK rm) * B^T (B NxK rm) + bias, fp32 out.  M,N %256==0, K%128==0.
// LDS: A 2x32KB @0, B 2x32KB @65536.  Staging ledger identical to R1
// (verified): ph1 B0(T+1), ph2 B1(T+1), ph4 A(T+2)+vmcnt4, ph5 B0(T+2),
// ph6 B1(T+2), ph8 A(T+3)+vmcnt4; tail iters drain with vmcnt0.
// B fragments (bg[4][2]) are loaded ONCE per K-tile and held in regs.
// ---------------------------------------------------------------------------
__global__ __launch_bounds__(512, 2)
void gemm256(const bf16* __restrict__ A, const bf16* __restrict__ B,
             float* __restrict__ C, const float* __restrict__ bias_p,
             int M, int N, int K) {
  extern __shared__ bf16 lds[];
  const int tid  = threadIdx.x;
  const int lane = tid & 63, wave = tid >> 6;
  const int wm = wave >> 2, wn = wave & 3;       // 2 x 4 waves
  const int fr = lane & 15, fq = lane >> 4;
  const int xm = (fr & 7) << 4;
  const int kx0 = (fq * 16) ^ xm;                // k-chunk byte, kk=0
  const int kx1 = (fq * 16 + 64) ^ xm;           // k-chunk byte, kk=1

  // XCD-aware block swizzle (nwg divisible by 8)
  const int nwg = gridDim.x;
  const int bid = blockIdx.x;
  const int swz = (bid & 7) * (nwg >> 3) + (bid >> 3);
  const int gx  = N >> 8;
  const int row0 = (swz / gx) << 8, col0 = (swz % gx) << 8;

  // staging source (pre-swizzled global column so linear gld_lds writes land
  // at LDS[row][col16 ^ (row&7)])
  const int srow = wave * 8 + (lane >> 3);
  const int scol = ((lane & 7) ^ (lane >> 3)) * 8;
  const bf16* Agl = A + (size_t)(row0 + srow) * K + scol;
  const bf16* Bgl = B + (size_t)(col0 + srow) * K + scol;

#define STG(gl, tb, t, h)                                                    \
  do {                                                                       \
    const size_t _k = (size_t)(t) * 64;                                      \
    GLD_LDS((gl) + (size_t)((h) * 128) * K + _k,                             \
            lds + (tb) + ((t) & 1) * 16384 + (h) * 8192 + wave * 512);       \
    GLD_LDS((gl) + (size_t)((h) * 128 + 64) * K + _k,                        \
            lds + (tb) + ((t) & 1) * 16384 + (h) * 8192 + 4096 + wave * 512);\
  } while (0)

  const char* ldsc = (const char*)lds;
  // 4 loop-invariant LDS read bases; every ds_read is base + literal offset.
  const char* Ab0 = ldsc + wm * 16384 + fr * 128 + kx0;
  const char* Ab1 = ldsc + wm * 16384 + fr * 128 + kx1;
  const char* Bb0 = ldsc + 65536 + wn * 8192 + fr * 128 + kx0;
  const char* Bb1 = ldsc + 65536 + wn * 8192 + fr * 128 + kx1;

  f32x4  acc[8][4] = {};
  bf16x8 af[4][2];   // current mg half of A fragments
  bf16x8 bg[4][2];   // ALL B fragments for the K-tile (held across phases)

#define LDA(mg, p)                                                           \
  do {                                                                       \
    _Pragma("unroll") for (int m_ = 0; m_ < 4; ++m_) {                       \
      af[m_][0] = *(const bf16x8*)(Ab0 + (p) * 32768 + ((mg) * 4 + m_) * 2048);\
      af[m_][1] = *(const bf16x8*)(Ab1 + (p) * 32768 + ((mg) * 4 + m_) * 2048);\
    }                                                                        \
  } while (0)

#define LDB(np, p)                                                           \
  do {                                                                       \
    _Pragma("unroll") for (int n_ = 0; n_ < 2; ++n_) {                       \
      bg[(np) * 2 + n_][0] =                                                 \
          *(const bf16x8*)(Bb0 + (p) * 32768 + ((np) * 2 + n_) * 2048);      \
      bg[(np) * 2 + n_][1] =                                                 \
          *(const bf16x8*)(Bb1 + (p) * 32768 + ((np) * 2 + n_) * 2048);      \
    }                                                                        \
  } while (0)

#define MM(mg, np)                                                           \
  do {                                                                       \
    _Pragma("unroll") for (int kk_ = 0; kk_ < 2; ++kk_)                      \
      _Pragma("unroll") for (int m_ = 0; m_ < 4; ++m_)                       \
        _Pragma("unroll") for (int n_ = 0; n_ < 2; ++n_)                     \
          acc[(mg) * 4 + m_][(np) * 2 + n_] =                                \
              __builtin_amdgcn_mfma_f32_16x16x32_bf16(                       \
                  af[m_][kk_], bg[(np) * 2 + n_][kk_],                       \
                  acc[(mg) * 4 + m_][(np) * 2 + n_], 0, 0, 0);               \
  } while (0)

  // prologue: tile0 (A,B full) + tile1 (A); B(1) staged in ph1/ph2
  STG(Agl, 0, 0, 0); STG(Agl, 0, 0, 1);
  STG(Bgl, 32768, 0, 0); STG(Bgl, 32768, 0, 1);
  STG(Agl, 0, 1, 0); STG(Agl, 0, 1, 1);
  WVM4(); BAR();

  const int NT = K >> 6;
  for (int T = 0; T < NT; T += 2) {
    const bool s2 = (T + 2 < NT), s3 = (T + 3 < NT);
    // ph1: reads af(mg0) + bg(np0) of buf0
    LDA(0, 0); LDB(0, 0);
    STG(Bgl, 32768, T + 1, 0);
    BAR(); PRIO1(); MM(0, 0); PRIO0(); BAR();
    // ph2: reads bg(np1)
    LDB(1, 0);
    STG(Bgl, 32768, T + 1, 1);
    BAR(); PRIO1(); MM(0, 1); PRIO0(); BAR();
    // ph3: reads af(mg1); bg held
    LDA(1, 0);
    BAR(); PRIO1(); MM(1, 0); PRIO0(); BAR();
    // ph4: no reads
    if (s2) { STG(Agl, 0, T + 2, 0); STG(Agl, 0, T + 2, 1); }
    BAR(); PRIO1(); MM(1, 1); PRIO0();
    if (s2) { WVM4(); } else { WVM0(); }
    BAR();
    // ph5
    LDA(0, 1); LDB(0, 1);
    if (s2) STG(Bgl, 32768, T + 2, 0);
    BAR(); PRIO1(); MM(0, 0); PRIO0(); BAR();
    // ph6
    LDB(1, 1);
    if (s2) STG(Bgl, 32768, T + 2, 1);
    BAR(); PRIO1(); MM(0, 1); PRIO0(); BAR();
    // ph7
    LDA(1, 1);
    BAR(); PRIO1(); MM(1, 0); PRIO0(); BAR();
    // ph8
    if (s3) { STG(Agl, 0, T + 3, 0); STG(Agl, 0, T + 3, 1); }
    BAR(); PRIO1(); MM(1, 1); PRIO0();
    if (s3) { WVM4(); } else { WVM0(); }
    BAR();
  }

  const float bias = bias_p[0];
#pragma unroll
  for (int m = 0; m < 8; ++m) {
#pragma unroll
    for (int n = 0; n < 4; ++n) {
      const int r = row0 + wm * 128 + m * 16 + fq * 4;
      const int c = col0 + wn * 64 + n * 16 + fr;
#pragma unroll
      for (int j = 0; j < 4; ++j)
        C[(size_t)(r + j) * N + c] = acc[m][n][j] + bias;
    }
  }
#undef STG
#undef LDA
#undef LDB
#undef MM
}

// ---------------------------------------------------------------------------
// m97-structure 128x128 GEMM (small XW = X*W^T, bf16 out)
// ---------------------------------------------------------------------------
__global__ void gemm_bt(const bf16* __restrict__ A, const bf16* __restrict__ B,
                        bf16* __restrict__ Cb, int M, int N, int K) {
  __shared__ bf16 As[128 * 32];
  __shared__ bf16 Bs[128 * 32];
  const int tid  = threadIdx.x;
  const int lane = tid & 63;
  const int wave = tid >> 6;
  const int wr = wave >> 1, wc = wave & 1;
  const int fr = lane & 15, fq = lane >> 4;
  const int row0 = blockIdx.y * 128, col0 = blockIdx.x * 128;

  f32x4 acc[4][4] = {};
  const int c0 = tid, c1 = 256 + tid;
  const bf16* Ag0 = A + (size_t)(row0 + (c0 >> 2)) * K + (c0 & 3) * 8;
  const bf16* Ag1 = A + (size_t)(row0 + (c1 >> 2)) * K + (c1 & 3) * 8;
  const bf16* Bg0 = B + (size_t)(col0 + (c0 >> 2)) * K + (c0 & 3) * 8;
  const bf16* Bg1 = B + (size_t)(col0 + (c1 >> 2)) * K + (c1 & 3) * 8;
  bf16* Al0 = As + (wave * 64) * 8;
  bf16* Al1 = As + (256 + wave * 64) * 8;
  bf16* Bl0 = Bs + (wave * 64) * 8;
  bf16* Bl1 = Bs + (256 + wave * 64) * 8;

  for (int k0 = 0; k0 < K; k0 += 32) {
    GLD_LDS(Ag0 + k0, Al0);
    GLD_LDS(Ag1 + k0, Al1);
    GLD_LDS(Bg0 + k0, Bl0);
    GLD_LDS(Bg1 + k0, Bl1);
    __syncthreads();
    bf16x8 af[4], bgf[4];
#pragma unroll
    for (int m = 0; m < 4; ++m)
      af[m] = *(const bf16x8*)&As[(wr * 64 + m * 16 + fr) * 32 + fq * 8];
#pragma unroll
    for (int n = 0; n < 4; ++n)
      bgf[n] = *(const bf16x8*)&Bs[(wc * 64 + n * 16 + fr) * 32 + fq * 8];
#pragma unroll
    for (int m = 0; m < 4; ++m)
#pragma unroll
      for (int n = 0; n < 4; ++n)
        acc[m][n] = __builtin_amdgcn_mfma_f32_16x16x32_bf16(af[m], bgf[n],
                                                            acc[m][n], 0, 0, 0);
    __syncthreads();
  }
#pragma unroll
  for (int m = 0; m < 4; ++m)
#pragma unroll
    for (int n = 0; n < 4; ++n) {
      const int r  = row0 + wr * 64 + m * 16 + fq * 4;
      const int cc = col0 + wc * 64 + n * 16 + fr;
#pragma unroll
      for (int j = 0; j < 4; ++j)
        Cb[(size_t)(r + j) * N + cc] = (bf16)acc[m][n][j];
    }
}

__global__ void cvt_f32_bf16(const float* __restrict__ in, bf16* __restrict__ out,
                             int n4) {
  int i = blockIdx.x * blockDim.x + threadIdx.x;
  if (i >= n4) return;
  const float4 v = ((const float4*)in)[i];
  bf16x4 o;
  o[0] = (bf16)v.x; o[1] = (bf16)v.y; o[2] = (bf16)v.z; o[3] = (bf16)v.w;
  ((bf16x4*)out)[i] = o;
}

__global__ void transpose_cvt_w(const float* __restrict__ W, bf16* __restrict__ Wt) {
  __shared__ float s[32][33];
  const int tx = threadIdx.x & 31;
  const int ty = threadIdx.x >> 5;
  const int n0 = blockIdx.x * 32;
  const int k0 = blockIdx.y * 32;
#pragma unroll
  for (int p = 0; p < 4; ++p)
    s[ty + p * 8][tx] = W[(size_t)(k0 + ty + p * 8) * 1024 + n0 + tx];
  __syncthreads();
#pragma unroll
  for (int p = 0; p < 4; ++p)
    Wt[(size_t)(n0 + ty + p * 8) * 1024 + k0 + tx] = (bf16)s[tx][ty + p * 8];
}

extern "C" void kernel_launch(void* const* d_in, const int* in_sizes, int n_in,
                              void* d_out, int out_size, void* d_ws, size_t ws_size,
                              hipStream_t stream) {
  const float* X = (const float*)d_in[0];   // (8192, 1024)
  const float* W = (const float*)d_in[1];   // (1024, 1024)
  const float* b = (const float*)d_in[2];   // (1,)
  float* out = (float*)d_out;               // (8192, 8192)

  const int Nn = 8192, D = 1024;
  char* ws = (char*)d_ws;
  bf16* Xb  = (bf16*)(ws);
  bf16* XWb = (bf16*)(ws + (size_t)16 * 1024 * 1024);
  bf16* Wt  = (bf16*)(ws + (size_t)32 * 1024 * 1024);

  cvt_f32_bf16<<<(Nn * D / 4 + 255) / 256, 256, 0, stream>>>(X, Xb, Nn * D / 4);
  transpose_cvt_w<<<dim3(D / 32, D / 32), 256, 0, stream>>>(W, Wt);
  gemm_bt<<<dim3(D / 128, Nn / 128), 256, 0, stream>>>(Xb, Wt, XWb, Nn, D, D);
  gemm256<<<(Nn / 256) * (Nn / 256), 512, 131072, stream>>>(XWb, Xb, out, b,
                                                            Nn, Nn, D);
}